// Round 2
// baseline (611.847 us; speedup 1.0000x reference)
//
#include <hip/hip_runtime.h>
#include <math.h>

#define BB 4
#define NN 2048
#define MM 2048
#define TPB 256
#define MCH 128
#define SLOT (BB*NN)   // 8192

// ws float layout:
// [0]        remainL  [BB*NN]
// [SLOT]     remainR  [BB*MM]
// [2*SLOT]   suml     [BB*NN]
// [3*SLOT]   sumr     [BB*MM]
// [4*SLOT]   rowsum   [BB*NN]
// [5*SLOT]   cost     [1]

__global__ void k_init(float* __restrict__ ws) {
    int i = blockIdx.x * blockDim.x + threadIdx.x;
    if (i < SLOT) {
        ws[i] = 1.0f;            // remainL (multiL = 1 since N==M)
        ws[SLOT + i] = 1.0f;     // remainR (multiR = 1)
        ws[2*SLOT + i] = 0.0f;   // suml
        ws[3*SLOT + i] = 0.0f;   // sumr
        ws[4*SLOT + i] = 0.0f;   // rowsum
    }
    if (i == 0) ws[5*SLOT] = 0.0f;  // cost
}

// Pass A: suml[b][n] = sum_m exp(level*d2(n,m)) * remainR[b][m]
__global__ void k_passA(const float* __restrict__ tpl, const float* __restrict__ src,
                        float* __restrict__ ws, float level) {
    __shared__ float4 sh[MCH];
    const int MCB = MM / MCH;   // 16
    const int RCB = NN / TPB;   // 8
    int bid = blockIdx.x;
    int mc = bid % MCB;
    int rc = (bid / MCB) % RCB;
    int b  = bid / (MCB * RCB);
    const float* remR = ws + SLOT;
    float* suml = ws + 2*SLOT;
    int tid = threadIdx.x;
    for (int i = tid; i < MCH; i += TPB) {
        int m = mc*MCH + i;
        const float* sp = src + (b*MM + m)*3;
        sh[i] = make_float4(sp[0], sp[1], sp[2], remR[b*MM + m]);
    }
    __syncthreads();
    int n = rc*TPB + tid;
    const float* tp = tpl + (b*NN + n)*3;
    float tx = tp[0], ty = tp[1], tz = tp[2];
    float acc = 0.0f;
#pragma unroll 4
    for (int i = 0; i < MCH; ++i) {
        float4 s = sh[i];
        float dx = tx - s.x, dy = ty - s.y, dz = tz - s.z;
        float d2 = dx*dx + dy*dy + dz*dz;
        acc += __expf(level * d2) * s.w;
    }
    atomicAdd(&suml[b*NN + n], acc);
}

// Pass B: sumr[b][m] = sum_n exp(level*d2(n,m)) * ratioL[b][n]
// ratioL computed on the fly from remainL, suml.
__global__ void k_passB(const float* __restrict__ tpl, const float* __restrict__ src,
                        float* __restrict__ ws, float level) {
    __shared__ float4 sh[MCH];
    const int NCB = NN / MCH;   // 16
    const int CCB = MM / TPB;   // 8
    int bid = blockIdx.x;
    int nc = bid % NCB;
    int cc = (bid / NCB) % CCB;
    int b  = bid / (NCB * CCB);
    const float* remL = ws;
    const float* suml = ws + 2*SLOT;
    float* sumr = ws + 3*SLOT;
    int tid = threadIdx.x;
    for (int i = tid; i < MCH; i += TPB) {
        int n = nc*MCH + i;
        const float* tp = tpl + (b*NN + n)*3;
        float rl = remL[b*NN + n] / (suml[b*NN + n] + 1e-9f);
        sh[i] = make_float4(tp[0], tp[1], tp[2], rl);
    }
    __syncthreads();
    int m = cc*TPB + tid;
    const float* sp = src + (b*MM + m)*3;
    float sx = sp[0], sy = sp[1], sz = sp[2];
    float acc = 0.0f;
#pragma unroll 4
    for (int i = 0; i < MCH; ++i) {
        float4 t = sh[i];
        float dx = t.x - sx, dy = t.y - sy, dz = t.z - sz;
        float d2 = dx*dx + dy*dy + dz*dz;
        acc += __expf(level * d2) * t.w;
    }
    atomicAdd(&sumr[b*MM + m], acc);
}

// Pass C: rowsum[b][n] = sum_m w0 * ratioR[m];  cost += ratioL[n] * sum_m w0*ratioR[m]*dist
__global__ void k_passC(const float* __restrict__ tpl, const float* __restrict__ src,
                        float* __restrict__ ws, float level) {
    __shared__ float4 sh[MCH];
    const int MCB = MM / MCH;
    const int RCB = NN / TPB;
    int bid = blockIdx.x;
    int mc = bid % MCB;
    int rc = (bid / MCB) % RCB;
    int b  = bid / (MCB * RCB);
    const float* remL = ws;
    const float* remR = ws + SLOT;
    const float* suml = ws + 2*SLOT;
    const float* sumr = ws + 3*SLOT;
    float* rowsum = ws + 4*SLOT;
    float* cost = ws + 5*SLOT;
    int tid = threadIdx.x;
    for (int i = tid; i < MCH; i += TPB) {
        int m = mc*MCH + i;
        const float* sp = src + (b*MM + m)*3;
        float rr = remR[b*MM + m] / (sumr[b*MM + m] + 1e-9f);
        sh[i] = make_float4(sp[0], sp[1], sp[2], rr);
    }
    __syncthreads();
    int n = rc*TPB + tid;
    const float* tp = tpl + (b*NN + n)*3;
    float tx = tp[0], ty = tp[1], tz = tp[2];
    float racc = 0.0f, cacc = 0.0f;
#pragma unroll 4
    for (int i = 0; i < MCH; ++i) {
        float4 s = sh[i];
        float dx = tx - s.x, dy = ty - s.y, dz = tz - s.z;
        float d2 = dx*dx + dy*dy + dz*dz;
        float t = __expf(level * d2) * s.w;
        racc += t;
        cacc += t * sqrtf(fmaxf(d2, 1e-24f));
    }
    atomicAdd(&rowsum[b*NN + n], racc);
    float rl = remL[b*NN + n] / (suml[b*NN + n] + 1e-9f);
    float v = rl * cacc * (1.0f / (float)(BB * NN));
    // wave-level reduction, then one atomic per wave
#pragma unroll
    for (int off = 32; off > 0; off >>= 1) v += __shfl_down(v, off, 64);
    if ((tid & 63) == 0) atomicAdd(cost, v);
}

// Pass D: update remainL/remainR, zero accumulators for next level.
__global__ void k_passD(float* __restrict__ ws) {
    int i = blockIdx.x * blockDim.x + threadIdx.x;   // over SLOT (N==M)
    float* remL = ws;
    float* remR = ws + SLOT;
    float* suml = ws + 2*SLOT;
    float* sumr = ws + 3*SLOT;
    float* rowsum = ws + 4*SLOT;
    float rl = remL[i], sl = suml[i], rs = rowsum[i];
    float ratioL = rl / (sl + 1e-9f);
    remL[i] = fmaxf(rl - ratioL * rs, 0.0f);
    float rr = remR[i], sr = sumr[i];
    float ratioR = rr / (sr + 1e-9f);
    remR[i] = fmaxf(rr - ratioR * sr, 0.0f);   // colsum = ratioR * sumr_raw (exact)
    suml[i] = 0.0f; sumr[i] = 0.0f; rowsum[i] = 0.0f;
}

__global__ void k_final(const float* __restrict__ ws, float* __restrict__ out) {
    out[0] = ws[5*SLOT];
}

extern "C" void kernel_launch(void* const* d_in, const int* in_sizes, int n_in,
                              void* d_out, int out_size, void* d_ws, size_t ws_size,
                              hipStream_t stream) {
    const float* tpl = (const float*)d_in[0];
    const float* src = (const float*)d_in[1];
    float* ws = (float*)d_ws;
    float* out = (float*)d_out;

    k_init<<<SLOT/TPB, TPB, 0, stream>>>(ws);

    const float levels[10] = {-16384.0f, -4096.0f, -1024.0f, -256.0f, -64.0f,
                              -16.0f, -4.0f, -1.0f, -0.25f, 0.0f};
    const int gridRow = BB * (NN/TPB) * (MM/MCH);  // 512
    const int gridCol = BB * (MM/TPB) * (NN/MCH);  // 512

    for (int k = 0; k < 10; ++k) {
        k_passA<<<gridRow, TPB, 0, stream>>>(tpl, src, ws, levels[k]);
        k_passB<<<gridCol, TPB, 0, stream>>>(tpl, src, ws, levels[k]);
        k_passC<<<gridRow, TPB, 0, stream>>>(tpl, src, ws, levels[k]);
        k_passD<<<SLOT/TPB, TPB, 0, stream>>>(ws);
    }
    k_final<<<1, 1, 0, stream>>>(ws, out);
}